// Round 2
// baseline (1747.392 us; speedup 1.0000x reference)
//
#include <hip/hip_runtime.h>

#define Nn 2048
#define Dd 128
#define BM 64
#define BN 64
#define VS 36   // V^T row stride in words

typedef __attribute__((ext_vector_type(8))) short short8;
typedef __attribute__((ext_vector_type(4))) float f32x4;
typedef __attribute__((ext_vector_type(2))) unsigned int u32x2;
typedef __attribute__((ext_vector_type(4))) unsigned int u32x4;

__device__ __forceinline__ unsigned int pack2(float x, float y){
  // two fp32 -> packed bf16x2 (RNE), low half = x
  unsigned int ux = __float_as_uint(x);
  ux += 0x7fffu + ((ux >> 16) & 1u);
  unsigned int uy = __float_as_uint(y);
  uy += 0x7fffu + ((uy >> 16) & 1u);
  return (ux >> 16) | (uy & 0xffff0000u);
}

extern "C" __global__ void __launch_bounds__(256, 4)
attn_kernel(const float* __restrict__ qg, const float* __restrict__ kg,
            const float* __restrict__ vg, float* __restrict__ attn,
            float* __restrict__ outp)
{
  // Only V lives in LDS now, double-buffered: 2 * 18432 B = 36864 B -> 4 blocks/CU
  __shared__ unsigned int Vt[2][Dd * VS];

  const int tid  = threadIdx.x;
  const int x    = (int)gridDim.x - 1 - (int)blockIdx.x;  // heavy tiles first
  const int b    = blockIdx.y;
  const int n0   = x * BM;
  const int T    = x + 1;
  const int lane = tid & 63;
  const int wv   = tid >> 6;      // wave 0..3: owns S rows wv*16..+15
  const int a    = lane & 15;
  const int q    = lane >> 4;
  const int rloc = wv * 16 + a;   // this lane's S row (local)
  const float inv_scale = 0.08838834764831845f;  // 1/sqrt(128)

  // ---- Q fragments in registers (16 VGPRs), loaded + packed once ----
  short8 qf[4];
  {
    const float* qsrc = qg + ((size_t)b * Nn + n0 + rloc) * Dd;
    #pragma unroll
    for (int kk = 0; kk < 4; ++kk){
      const f32x4 a0 = *(const f32x4*)(qsrc + kk * 32 + q * 8);
      const f32x4 a1 = *(const f32x4*)(qsrc + kk * 32 + q * 8 + 4);
      u32x4 w;
      w.x = pack2(a0.x, a0.y); w.y = pack2(a0.z, a0.w);
      w.z = pack2(a1.x, a1.y); w.w = pack2(a1.z, a1.w);
      qf[kk] = __builtin_bit_cast(short8, w);
    }
  }

  const float* kb0 = kg + (size_t)b * Nn * Dd;

  // QK^T for one K-tile: fragments straight from global (L1/L2-cached,
  // 4x wave redundancy). No LDS, no barriers, no staging VALU on shared path.
  auto qk_tile = [&](int tk, f32x4* acc){
    const float* kt = kb0 + (size_t)tk * BN * Dd;
    #pragma unroll
    for (int kk = 0; kk < 4; ++kk){
      #pragma unroll
      for (int tc = 0; tc < 4; ++tc){
        const float* s = kt + (tc * 16 + a) * Dd + kk * 32 + q * 8;
        const f32x4 r0 = *(const f32x4*)s;
        const f32x4 r1 = *(const f32x4*)(s + 4);
        u32x4 w;
        w.x = pack2(r0.x, r0.y); w.y = pack2(r0.z, r0.w);
        w.z = pack2(r1.x, r1.y); w.w = pack2(r1.z, r1.w);
        acc[tc] = __builtin_amdgcn_mfma_f32_16x16x32_bf16(
            __builtin_bit_cast(short8, w), qf[kk], acc[tc], 0, 0, 0);
      }
    }
  };

  // ================= phase 1: per-row sum of exp (barrier-free) ==========
  f32x4 lpv = (f32x4)0.0f;   // 4 independent accumulation chains (one per r)
  for (int tk = 0; tk < T; ++tk){
    f32x4 acc[4];
    #pragma unroll
    for (int tc = 0; tc < 4; ++tc) acc[tc] = (f32x4)0.0f;
    qk_tile(tk, acc);
    if (tk == x){
      #pragma unroll
      for (int tc = 0; tc < 4; ++tc)
        #pragma unroll
        for (int r = 0; r < 4; ++r){
          const int col = tc * 16 + q * 4 + r;
          if (col <= rloc) lpv[r] += __expf(acc[tc][r] * inv_scale);
        }
    } else {
      #pragma unroll
      for (int tc = 0; tc < 4; ++tc)
        #pragma unroll
        for (int r = 0; r < 4; ++r)
          lpv[r] += __expf(acc[tc][r] * inv_scale);
    }
  }
  float lp = (lpv.x + lpv.y) + (lpv.z + lpv.w);
  lp += __shfl_xor(lp, 16);
  lp += __shfl_xor(lp, 32);
  const float rl = 1.0f / lp;

  // ================= phase 2 (reverse tile order for L2 reuse) ============
  f32x4 acco[8];
  #pragma unroll
  for (int tc = 0; tc < 8; ++tc) acco[tc] = (f32x4)0.0f;

  f32x4 vb[8];
  const int vmp = tid & 31, vd0 = (tid >> 5) * 16;
  auto loadV = [&](int tk){
    const float* s0 = vg + ((size_t)b * Nn + (size_t)tk * BN + 2 * vmp) * Dd + vd0;
    #pragma unroll
    for (int j = 0; j < 4; ++j){
      vb[j]     = *(const f32x4*)(s0 + j * 4);
      vb[4 + j] = *(const f32x4*)(s0 + Dd + j * 4);
    }
  };
  auto storeV = [&](int bi){
    unsigned int* B = &Vt[bi][0];
    #pragma unroll
    for (int j = 0; j < 4; ++j){
      B[(vd0 + j*4 + 0) * VS + vmp] = pack2(vb[j].x, vb[4+j].x);
      B[(vd0 + j*4 + 1) * VS + vmp] = pack2(vb[j].y, vb[4+j].y);
      B[(vd0 + j*4 + 2) * VS + vmp] = pack2(vb[j].z, vb[4+j].z);
      B[(vd0 + j*4 + 3) * VS + vmp] = pack2(vb[j].w, vb[4+j].w);
    }
  };

  int cur = 0;
  loadV(T - 1);
  storeV(0);
  __syncthreads();   // Vt[0] ready

  for (int i = 0; i < T; ++i){
    const int tk = T - 1 - i;

    f32x4 acc[4];
    #pragma unroll
    for (int tc = 0; tc < 4; ++tc) acc[tc] = (f32x4)0.0f;
    qk_tile(tk, acc);

    if (i + 1 < T) loadV(tk - 1);   // prefetch next V tile into regs

    const bool diag = (tk == x);
    const size_t arow = ((size_t)b * Nn + n0 + rloc) * (size_t)Nn + (size_t)tk * BN;
    // P packed bf16 pairs kept in registers: Wp[tc][bb] = cols (tc*16+q*4+2bb, +1)
    unsigned int Wp[4][2];
    #pragma unroll
    for (int tc = 0; tc < 4; ++tc){
      f32x4 p;
      #pragma unroll
      for (int r = 0; r < 4; ++r){
        const int col = tc * 16 + q * 4 + r;
        float e = __expf(acc[tc][r] * inv_scale) * rl;
        if (diag && col > rloc) e = 0.0f;
        p[r] = e;
      }
      *(f32x4*)(attn + arow + tc * 16 + q * 4) = p;   // dwordx4 store
      Wp[tc][0] = pack2(p.x, p.y);
      Wp[tc][1] = pack2(p.z, p.w);
    }

    // PV: redistribute P across the 4 q-lanes in-register.
    // target lane q, slot (kk,j): src lane qs = (2q + (j>>1))&3,
    //                             src reg Wp[kk*2 + (q>>1)][j&1]
    #pragma unroll
    for (int kk = 0; kk < 2; ++kk){
      u32x4 F;
      #pragma unroll
      for (int j = 0; j < 4; ++j){
        const int src = (((2 * q + (j >> 1)) & 3) << 4) | a;
        const unsigned int v0 = (unsigned int)__shfl((int)Wp[kk*2 + 0][j & 1], src, 64);
        const unsigned int v1 = (unsigned int)__shfl((int)Wp[kk*2 + 1][j & 1], src, 64);
        F[j] = (q & 2) ? v1 : v0;
      }
      const short8 pf = __builtin_bit_cast(short8, F);
      #pragma unroll
      for (int tc = 0; tc < 8; ++tc){
        const short8 vf = __builtin_bit_cast(short8,
            *(const u32x4*)&Vt[cur][(tc * 16 + a) * VS + kk * 16 + q * 4]);
        acco[tc] = __builtin_amdgcn_mfma_f32_16x16x32_bf16(pf, vf, acco[tc], 0, 0, 0);
      }
    }

    if (i + 1 < T){
      storeV(cur ^ 1);     // write the OTHER buffer; readers of cur are done in-wave
      __syncthreads();     // one barrier per iteration: publishes cur^1, retires cur
      cur ^= 1;
    }
  }

  // ---- epilogue: O tile -> out (C-layout: row=q*4+r, col=a) ----
  {
    float* orow = outp + ((size_t)b * Nn + n0) * Dd;
    #pragma unroll
    for (int tc = 0; tc < 8; ++tc)
      #pragma unroll
      for (int r = 0; r < 4; ++r)
        orow[(size_t)(wv * 16 + q * 4 + r) * Dd + tc * 16 + a] = acco[tc][r];
  }

  // ---- zero-fill masked upper region LAST (drains at kernel end, no barrier) ----
  {
    const int mEnd = T * BN;
    float* zrow = attn + ((size_t)b * Nn + n0 + (tid >> 2)) * (size_t)Nn;
    const f32x4 z = (f32x4)0.0f;
    for (int cc = mEnd + (tid & 3) * 4; cc < Nn; cc += 16)
      *(f32x4*)(zrow + cc) = z;
  }
}

extern "C" void kernel_launch(void* const* d_in, const int* in_sizes, int n_in,
                              void* d_out, int out_size, void* d_ws, size_t ws_size,
                              hipStream_t stream) {
  const float* q = (const float*)d_in[0];
  const float* k = (const float*)d_in[1];
  const float* v = (const float*)d_in[2];
  float* attn = (float*)d_out;
  float* out  = attn + (size_t)32 * Nn * Nn;
  dim3 grid(32, 32), block(256);
  attn_kernel<<<grid, block, 0, stream>>>(q, k, v, attn, out);
  (void)in_sizes; (void)n_in; (void)out_size; (void)d_ws; (void)ws_size;
}